// Round 15
// baseline (253.241 us; speedup 1.0000x reference)
//
#include <hip/hip_runtime.h>
#include <hip/hip_bf16.h>

typedef __attribute__((ext_vector_type(8))) short bf16x8;
typedef __attribute__((ext_vector_type(4))) float f32x4;
typedef __attribute__((ext_vector_type(4))) short s16x4;
typedef __attribute__((ext_vector_type(4))) unsigned u32x4;

#define GLOBAL_AS(p) ((const __attribute__((address_space(1))) void*)(p))
#define LDS_AS(p)    ((__attribute__((address_space(3))) void*)(p))

__device__ __forceinline__ short f2bf(float f) {
  return __builtin_bit_cast(short, __float2bfloat16(f));   // HW RNE cvt
}
__device__ __forceinline__ float bf2f(short s) {
  return __bfloat162float(__builtin_bit_cast(__hip_bfloat16, s));
}
__device__ __forceinline__ unsigned packbf(float a, float b) {
  return (unsigned)(unsigned short)f2bf(a) | ((unsigned)(unsigned short)f2bf(b) << 16);
}

// ---------------- merged weight prep + rmsnorm1 (one dispatch) ----------------
// bid 0..767: pack WQ/WK/WV; 768..1023: WO^T; 1024..2047: W1^T; 2048..3071: W2^T
// bid 3072..7167: rmsnorm row (bid-3072) of x -> h1
__global__ __launch_bounds__(256) void prep_kernel(
    const float* __restrict__ WQ, const float* __restrict__ WK,
    const float* __restrict__ WV, short* __restrict__ wqkv_t,
    const float* __restrict__ WO, short* __restrict__ wo_t,
    const float* __restrict__ W1, short* __restrict__ w1_t,
    const float* __restrict__ W2, short* __restrict__ w2_t,
    const float* __restrict__ x, const float* __restrict__ g1,
    short* __restrict__ h1) {
  __shared__ short Ls[64][66];
  __shared__ float red[4];
  const int tid = threadIdx.x;
  const int l = tid & 63, q4 = tid >> 6;
  const int bid = blockIdx.x;

  if (bid >= 3072) {
    const int row = bid - 3072;
    const float4 xv = *(const float4*)&x[(size_t)row * 1024 + tid * 4];
    float ss = xv.x * xv.x + xv.y * xv.y + xv.z * xv.z + xv.w * xv.w;
#pragma unroll
    for (int off = 32; off; off >>= 1) ss += __shfl_xor(ss, off);
    if ((tid & 63) == 0) red[tid >> 6] = ss;
    __syncthreads();
    float tot = red[0] + red[1] + red[2] + red[3];
    float scale = rsqrtf(tot / 1024.f + 1e-6f);
    const float4 gv = *(const float4*)&g1[tid * 4];
    s16x4 o;
    o[0] = f2bf(xv.x * scale * gv.x);
    o[1] = f2bf(xv.y * scale * gv.y);
    o[2] = f2bf(xv.z * scale * gv.z);
    o[3] = f2bf(xv.w * scale * gv.w);
    *(s16x4*)&h1[(size_t)row * 1024 + tid * 4] = o;
    return;
  }

  if (bid < 768) {
    const int xb = bid & 15, y = bid >> 4;
    const int hh = y & 15, proj = y >> 4;
    const float* W = (proj == 0) ? WQ : ((proj == 1) ? WK : WV);
    const float scl = (proj == 0) ? 0.125f : 1.f;
    const int d0 = xb * 64;
#pragma unroll
    for (int rep = 0; rep < 16; ++rep) {
      int dd = q4 * 16 + rep;
      Ls[dd][l] = f2bf(W[(size_t)hh * 65536 + (size_t)(d0 + dd) * 64 + l] * scl);
    }
    __syncthreads();
#pragma unroll
    for (int rep = 0; rep < 16; ++rep) {
      int ee = q4 * 16 + rep;
      wqkv_t[(size_t)(proj * 1024 + hh * 64 + ee) * 1024 + d0 + l] = Ls[l][ee];
    }
  } else {
    const float* in; short* out; int R, C, bx, by;
    if (bid < 1024) {
      int idx = bid - 768;  in = WO; out = wo_t; R = 1024; C = 1024;
      bx = idx & 15; by = idx >> 4;
    } else if (bid < 2048) {
      int idx = bid - 1024; in = W1; out = w1_t; R = 1024; C = 4096;
      bx = idx & 63; by = idx >> 6;
    } else {
      int idx = bid - 2048; in = W2; out = w2_t; R = 4096; C = 1024;
      bx = idx & 15; by = idx >> 4;
    }
    const int c0 = bx * 64, r0 = by * 64;
#pragma unroll
    for (int rep = 0; rep < 16; ++rep) {
      int rr = q4 * 16 + rep;
      Ls[rr][l] = f2bf(in[(size_t)(r0 + rr) * C + c0 + l]);
    }
    __syncthreads();
#pragma unroll
    for (int rep = 0; rep < 16; ++rep) {
      int cc = q4 * 16 + rep;
      out[(size_t)(c0 + cc) * R + r0 + l] = Ls[l][cc];
    }
  }
}

// V columns of qkv [S][3072] (cols 2048..3071) -> vt [1024][S], bf16->bf16
__global__ __launch_bounds__(256) void transpose_v_kernel(
    const short* __restrict__ qkv, short* __restrict__ vt, int S) {
  __shared__ short Ls[64][66];
  const int tid = threadIdx.x;
  const int l = tid & 63, q4 = tid >> 6;
  const int s0 = blockIdx.x * 64, e0 = blockIdx.y * 64;
#pragma unroll
  for (int rep = 0; rep < 16; ++rep) {
    int rr = q4 * 16 + rep;
    Ls[rr][l] = qkv[(size_t)(s0 + rr) * 3072 + 2048 + e0 + l];
  }
  __syncthreads();
#pragma unroll
  for (int rep = 0; rep < 16; ++rep) {
    int ee = q4 * 16 + rep;
    vt[(size_t)(e0 + ee) * S + s0 + l] = Ls[l][ee];
  }
}

// ---------------- RMSNorm (fp32 in -> bf16 out) ----------------
__global__ __launch_bounds__(256) void rmsnorm_kernel(
    const float* __restrict__ x, const float* __restrict__ g,
    short* __restrict__ out, int D) {
  const int row = blockIdx.x;
  const int tid = threadIdx.x;
  const float4 xv = *(const float4*)&x[(size_t)row * D + tid * 4];
  float ss = xv.x * xv.x + xv.y * xv.y + xv.z * xv.z + xv.w * xv.w;
#pragma unroll
  for (int off = 32; off; off >>= 1) ss += __shfl_xor(ss, off);
  __shared__ float red[4];
  if ((tid & 63) == 0) red[tid >> 6] = ss;
  __syncthreads();
  float tot = red[0] + red[1] + red[2] + red[3];
  float scale = rsqrtf(tot / (float)D + 1e-6f);
  const float4 gv = *(const float4*)&g[tid * 4];
  s16x4 o;
  o[0] = f2bf(xv.x * scale * gv.x);
  o[1] = f2bf(xv.y * scale * gv.y);
  o[2] = f2bf(xv.z * scale * gv.z);
  o[3] = f2bf(xv.w * scale * gv.w);
  *(s16x4*)&out[(size_t)row * D + tid * 4] = o;
}

// ---------------- 128x64 GEMM (WO): C = A[M,K] x BT[N,K]^T, fp32 out + addend ----------------
__global__ __launch_bounds__(256) void gemm_bt64_kernel(
    const short* __restrict__ A, const short* __restrict__ BT,
    int M, int N, int K,
    float* __restrict__ outF, const float* __restrict__ addend) {
  __shared__ short As[128 * 32];
  __shared__ short Bs[64 * 32];
  const int tid = threadIdx.x;
  const int lane = tid & 63;
  const int wid = tid >> 6;
  const int lrow = lane & 15;
  const int kk = lane >> 4;
  const int row0 = blockIdx.y * 128;
  const int col0 = blockIdx.x * 64;
  const int wm = wid >> 1, wn = wid & 1;

  f32x4 acc[4][2] = {};

  for (int k0 = 0; k0 < K; k0 += 32) {
    __syncthreads();
#pragma unroll
    for (int it = 0; it < 2; ++it) {
      int c = it * 256 + tid;
      int r = c >> 2, c8 = (c & 3) * 8;
      const short* ga = A + (size_t)(row0 + r) * K + k0 + c8;
      short* la = &As[(size_t)(it * 256 + wid * 64) * 8];
      __builtin_amdgcn_global_load_lds(GLOBAL_AS(ga), LDS_AS(la), 16, 0, 0);
    }
    {
      int r = tid >> 2, c8 = (tid & 3) * 8;
      const short* gb = BT + (size_t)(col0 + r) * K + k0 + c8;
      short* lb = &Bs[(size_t)(wid * 64) * 8];
      __builtin_amdgcn_global_load_lds(GLOBAL_AS(gb), LDS_AS(lb), 16, 0, 0);
    }
    __syncthreads();

    bf16x8 a[4], b[2];
#pragma unroll
    for (int i = 0; i < 4; ++i)
      a[i] = *(const bf16x8*)&As[(wm * 64 + i * 16 + lrow) * 32 + kk * 8];
#pragma unroll
    for (int j = 0; j < 2; ++j)
      b[j] = *(const bf16x8*)&Bs[(wn * 32 + j * 16 + lrow) * 32 + kk * 8];
#pragma unroll
    for (int i = 0; i < 4; ++i)
#pragma unroll
      for (int j = 0; j < 2; ++j)
        acc[i][j] = __builtin_amdgcn_mfma_f32_16x16x32_bf16(a[i], b[j], acc[i][j], 0, 0, 0);
  }

#pragma unroll
  for (int i = 0; i < 4; ++i) {
    int row = row0 + wm * 64 + i * 16 + kk * 4;
#pragma unroll
    for (int j = 0; j < 2; ++j) {
      int col = col0 + wn * 32 + j * 16 + lrow;
#pragma unroll
      for (int r = 0; r < 4; ++r) {
        size_t o = (size_t)(row + r) * N + col;
        outF[o] = acc[i][j][r] + addend[o];
      }
    }
  }
}

// ---------------- 256x256 8-phase GEMM (T2+T3+T4+T5), bf16 out ----------------
#define READ_A(buf, mh)                                                      \
  _Pragma("unroll") for (int m4 = 0; m4 < 4; ++m4) {                         \
    int row_ = wm * 128 + ((mh)*4 + m4) * 16 + lrow;                         \
    _Pragma("unroll") for (int k_ = 0; k_ < 2; ++k_) {                       \
      int sl_ = (k_ * 4 + kk) ^ (row_ & 7);                                  \
      aA[m4][k_] = *(const bf16x8*)&lds[buf][0][row_ * 64 + sl_ * 8];        \
    }                                                                        \
  }
#define READ_B2(buf, pr)                                                     \
  _Pragma("unroll") for (int nn = 0; nn < 2; ++nn) {                         \
    int n_ = (pr)*2 + nn;                                                    \
    int row_ = wn * 64 + n_ * 16 + lrow;                                     \
    _Pragma("unroll") for (int k_ = 0; k_ < 2; ++k_) {                       \
      int sl_ = (k_ * 4 + kk) ^ (row_ & 7);                                  \
      bB[n_][k_] = *(const bf16x8*)&lds[buf][1][row_ * 64 + sl_ * 8];        \
    }                                                                        \
  }
#define MFMA16(mh, nh)                                                       \
  _Pragma("unroll") for (int m4 = 0; m4 < 4; ++m4)                           \
  _Pragma("unroll") for (int n2 = 0; n2 < 2; ++n2)                           \
  _Pragma("unroll") for (int k_ = 0; k_ < 2; ++k_)                           \
    acc[(mh)*4 + m4][(nh)*2 + n2] = __builtin_amdgcn_mfma_f32_16x16x32_bf16( \
        aA[m4][k_], bB[(nh)*2 + n2][k_], acc[(mh)*4 + m4][(nh)*2 + n2], 0, 0, 0);
#define STAGE_HALF(buf, mat, half, kt)                                       \
  {                                                                          \
    const short* g_ = ((mat) ? Bb : Ab) + (size_t)((half)*128) * K + (kt)*64;\
    short* l_ = &lds[buf][mat][(half)*8192];                                 \
    _Pragma("unroll") for (int it_ = 0; it_ < 2; ++it_) {                    \
      int ci_ = it_ * 512 + tid;                                             \
      int r_ = ci_ >> 3, sl_ = (ci_ & 7) ^ (r_ & 7);                         \
      __builtin_amdgcn_global_load_lds(GLOBAL_AS(g_ + (size_t)r_ * K + sl_ * 8), \
                                       LDS_AS(l_ + ci_ * 8), 16, 0, 0);      \
    }                                                                        \
  }
#define PH_SYNC1()                                                           \
  __builtin_amdgcn_s_barrier();                                              \
  asm volatile("s_waitcnt lgkmcnt(0)" ::: "memory");                         \
  __builtin_amdgcn_sched_barrier(0);                                         \
  __builtin_amdgcn_s_setprio(1)
#define PH_SYNC2()                                                           \
  __builtin_amdgcn_s_setprio(0);                                             \
  __builtin_amdgcn_s_barrier()
#define PH_SYNC2_VM(n)                                                       \
  __builtin_amdgcn_s_setprio(0);                                             \
  asm volatile("s_waitcnt vmcnt(" #n ")" ::: "memory");                      \
  __builtin_amdgcn_s_barrier()

template <int EPI>
__global__ __launch_bounds__(512, 2) void gemm256_kernel(
    const short* __restrict__ A, const short* __restrict__ BT,
    int N, int K, int kslice, size_t pstride,
    short* __restrict__ outB, const float* __restrict__ bias) {
  __shared__ short lds[2][2][16384];   // [buf][A/B][256 rows x 64 k], 128 KiB
  const int tid = threadIdx.x;
  const int lane = tid & 63, wid = tid >> 6;
  const int lrow = lane & 15, kk = lane >> 4;
  const int wm = wid >> 2, wn = wid & 3;
  const int row0 = blockIdx.y * 256, col0 = blockIdx.x * 256;
  const int kbase = blockIdx.z * kslice;
  const int NT = kslice >> 6;

  const short* Ab = A + (size_t)row0 * K + kbase;
  const short* Bb = BT + (size_t)col0 * K + kbase;

  f32x4 acc[8][4] = {};
  bf16x8 aA[4][2], bB[4][2];

  STAGE_HALF(0, 1, 0, 0); STAGE_HALF(0, 0, 0, 0);
  STAGE_HALF(0, 1, 1, 0); STAGE_HALF(0, 0, 1, 0);
  STAGE_HALF(1, 1, 0, 1); STAGE_HALF(1, 0, 0, 1); STAGE_HALF(1, 0, 1, 1);
  asm volatile("s_waitcnt vmcnt(6)" ::: "memory");
  __builtin_amdgcn_s_barrier();

  const int iters = NT >> 1;
  for (int i = 0; i < iters; ++i) {
    const int t1 = 2 * i + 1;
    int kt2 = 2 * i + 2; if (kt2 >= NT) kt2 -= NT;
    int kt3 = 2 * i + 3; if (kt3 >= NT) kt3 -= NT;
    READ_A(0, 0); READ_B2(0, 0); STAGE_HALF(1, 1, 1, t1);
    PH_SYNC1(); MFMA16(0, 0); PH_SYNC2();
    READ_B2(0, 1);
    PH_SYNC1(); MFMA16(0, 1); PH_SYNC2();
    READ_A(0, 1); STAGE_HALF(0, 1, 0, kt2);
    PH_SYNC1(); MFMA16(1, 0); PH_SYNC2();
    STAGE_HALF(0, 0, 0, kt2);
    PH_SYNC1(); MFMA16(1, 1); PH_SYNC2_VM(4);
    READ_A(1, 0); READ_B2(1, 0); STAGE_HALF(0, 1, 1, kt2);
    PH_SYNC1(); MFMA16(0, 0); PH_SYNC2();
    READ_B2(1, 1); STAGE_HALF(0, 0, 1, kt2);
    PH_SYNC1(); MFMA16(0, 1); PH_SYNC2();
    READ_A(1, 1); STAGE_HALF(1, 1, 0, kt3);
    PH_SYNC1(); MFMA16(1, 0); PH_SYNC2();
    STAGE_HALF(1, 0, 0, kt3); STAGE_HALF(1, 0, 1, kt3);
    PH_SYNC1(); MFMA16(1, 1); PH_SYNC2_VM(6);
  }

  short* ob = outB + (size_t)blockIdx.z * pstride;
#pragma unroll
  for (int m = 0; m < 8; ++m) {
    int row = row0 + wm * 128 + m * 16 + kk * 4;
#pragma unroll
    for (int n = 0; n < 4; ++n) {
      int col = col0 + wn * 64 + n * 16 + lrow;
#pragma unroll
      for (int r = 0; r < 4; ++r) {
        float v = acc[m][n][r];
        size_t o = (size_t)(row + r) * N + col;
        if (EPI == 0) {
          ob[o] = f2bf(v);
        } else {
          v += bias[col];
          ob[o] = f2bf(v > 0.f ? v : 0.f);
        }
      }
    }
  }
}

// out[i] = sum_{s<4} part[s][i] + bias[i % 1024] + addend[i]   (W2 split-K reduce)
__global__ __launch_bounds__(256) void reduce4_kernel(
    const short* __restrict__ part, const float* __restrict__ bias,
    const float* __restrict__ addend, float* __restrict__ out) {
  const size_t MN = (size_t)4096 * 1024;
  size_t i8 = ((size_t)blockIdx.x * 256 + threadIdx.x) * 8;
  bf16x8 p0 = *(const bf16x8*)&part[i8];
  bf16x8 p1 = *(const bf16x8*)&part[MN + i8];
  bf16x8 p2 = *(const bf16x8*)&part[2 * MN + i8];
  bf16x8 p3 = *(const bf16x8*)&part[3 * MN + i8];
  int col = (int)(i8 & 1023);
#pragma unroll
  for (int j = 0; j < 8; ++j) {
    float v = (bf2f(p0[j]) + bf2f(p1[j])) + (bf2f(p2[j]) + bf2f(p3[j]));
    out[i8 + j] = v + bias[col + j] + addend[i8 + j];
  }
}

// ---------------- flash attention v13: in-register P (no Ps LDS), 4 blocks/CU ----------------
// Swapped QK^T leaves lane (lrow,kk) with P[q=lrow][key=c*16+kk*4+r]. PV's
// A-frag needs P[lrow][ks*32+kk*8+j]; solving gives c=ks*2+(kk>>1),
// kk_src=(kk&1)*2+(j>>2), r=j&3 -> each pf dword is one packed pd[c][0|1]
// dword from lane ((kk&1)<<5)+lrow (dw0,1) or +16 (dw2,3). 16 shfl + 8 select
// per chunk replaces the LDS P round-trip: Ps freed -> LDS 32KB -> 4 blk/CU.
__device__ const unsigned char QT_SLOT[48] = {
    31, 31, 30, 15, 30, 29, 29, 28, 14, 28, 27, 27, 26, 13, 26, 25,
    25, 24, 12, 24, 23, 23, 22, 11, 22, 21, 21, 20, 10, 20, 19, 19,
    18,  9, 18, 17, 17, 16,  8, 16,  7,  6,  5,  4,  3,  2,  1,  0};
__device__ const unsigned char SP_SLOT[48] = {
    0, 1, 0, 0, 1, 0, 1, 0, 0, 1, 0, 1, 0, 0, 1, 0,
    1, 0, 0, 1, 0, 1, 0, 0, 1, 0, 1, 0, 0, 1, 0, 1,
    0, 0, 1, 0, 1, 0, 0, 1, 0, 0, 0, 0, 0, 0, 0, 0};

__global__ __launch_bounds__(512, 8) void attn_kernel(
    const short* __restrict__ QKV, const short* __restrict__ VT,
    float* __restrict__ opart, float* __restrict__ lpart,
    short* __restrict__ O) {
  const int S = 4096;
  __shared__ short Ks[2][64 * 64];
  __shared__ short Vs[2][64 * 64];

  const int tid = threadIdx.x;
  const int lane = tid & 63;
  const int w = tid >> 6;                     // 0..7
  const int lrow = lane & 15;
  const int kk = lane >> 4;
  const int bid = blockIdx.x;
  const int h = bid & 15;
  const int slot = bid >> 4;
  const int qtile = QT_SLOT[slot];
  const int sp = SP_SLOT[slot];
  const int T = 2 * qtile + 2;                // total 64-key tiles for this qtile
  const bool split = (qtile >= 16);
  const int half = qtile + 1;
  const int t0 = (split && sp) ? half : 0;
  const int t1 = (split && !sp) ? half : T;
  const int q0 = qtile * 128;
  const int qw = q0 + w * 16;                 // 16 q-rows per wave
  const int myq = qw + lrow;                  // this lane's q row (swapped layout)
  const int srcA = ((kk & 1) << 5) + lrow;    // P-exchange source lanes
  const int srcB = srcA + 16;
  const bool hiC = (kk >> 1) != 0;

  auto stage = [&](int buf, int t) {
    const int kv0 = t * 64;
    int krow = tid >> 3;                      // 64 rows x 8 slots
    int ksl = (tid & 7) ^ (krow & 7);
    const short* gk = QKV + (size_t)(kv0 + krow) * 3072 + 1024 + h * 64 + ksl * 8;
    const short* gv = VT + (size_t)(h * 64 + krow) * S + kv0 + ksl * 8;
    __builtin_amdgcn_global_load_lds(GLOBAL_AS(gk),
                                     LDS_AS(&Ks[buf][(w * 64) * 8]), 16, 0, 0);
    __builtin_amdgcn_global_load_lds(GLOBAL_AS(gv),
                                     LDS_AS(&Vs[buf][(w * 64) * 8]), 16, 0, 0);
  };

  bf16x8 qf[2];
#pragma unroll
  for (int half2 = 0; half2 < 2; ++half2)
    qf[half2] = *(const bf16x8*)&QKV[(size_t)(qw + lrow) * 3072 +
                                     h * 64 + half2 * 32 + kk * 8];

  float rs_acc = 0.f;
  f32x4 o_acc[4] = {};

  stage(0, t0);
  __syncthreads();
  int cur = 0;

  for (int t = t0; t < t1; ++t) {
    if (t + 1 < t1) stage(cur ^ 1, t + 1);    // prefetch next 64-key tile

    const int kvc = t * 64;
    if (kvc <= qw + 15) {
      // ---- QK^T (swapped): sc[c] row=key(kk*4+r), col=q(lrow) ----
      bf16x8 kf[4][2];
#pragma unroll
      for (int c = 0; c < 4; ++c)
#pragma unroll
        for (int half2 = 0; half2 < 2; ++half2) {
          int krow = c * 16 + lrow;
          kf[c][half2] = *(const bf16x8*)&Ks[cur][krow * 64 + (((half2 * 4 + kk) ^ (krow & 7)) * 8)];
        }
      f32x4 sc[4];
      __builtin_amdgcn_s_setprio(1);
#pragma unroll
      for (int c = 0; c < 4; ++c) {
        f32x4 z = {};
        z = __builtin_amdgcn_mfma_f32_16x16x32_bf16(kf[c][0], qf[0], z, 0, 0, 0);
        z = __builtin_amdgcn_mfma_f32_16x16x32_bf16(kf[c][1], qf[1], z, 0, 0, 0);
        sc[c] = z;
      }
      __builtin_amdgcn_s_setprio(0);

      // ---- softmax numerator: pack P in-register ----
      unsigned pd[4][2];
      if (kvc + 63 <= qw) {
#pragma unroll
        for (int c = 0; c < 4; ++c) {
          float p0 = __expf(sc[c][0]), p1 = __expf(sc[c][1]);
          float p2 = __expf(sc[c][2]), p3 = __expf(sc[c][3]);
          rs_acc += (p0 + p1) + (p2 + p3);
          pd[c][0] = packbf(p0, p1);
          pd[c][1] = packbf(p2, p3);
        }
      } else {
#pragma unroll
        for (int c = 0; c < 4; ++c) {
          const int keyb = kvc + c * 16 + kk * 4;
          float pv[4];
#pragma unroll
          for (int r = 0; r < 4; ++r) {
            float p = __expf(sc[c][r]);
            if (keyb + r > myq) p = 0.f;
            pv[r] = p;
          }
          rs_acc += (pv[0] + pv[1]) + (pv[2] + pv[3]);
          pd[c][0] = packbf(pv[0], pv[1]);
          pd[c][1] = packbf(pv[2], pv[3]);
        }
      }

      // ---- PV: build P A-frag via shfl exchange, 8 MFMA ----
#pragma unroll
      for (int ks = 0; ks < 2; ++ks) {
        unsigned a0 = __shfl((int)pd[ks * 2][0], srcA);
        unsigned b0 = __shfl((int)pd[ks * 2 + 1][0], srcA);
        unsigned a1 = __shfl((int)pd[ks * 2][1], srcA);
        unsigned b1 = __shfl((int)pd[ks * 2 + 1][1], srcA);
        unsigned a2 = __shfl((int)pd[ks * 2][0], srcB);
        unsigned b2 = __shfl((int)pd[ks * 2 + 1][0], srcB);
        unsigned a3 = __shfl((int)pd[ks * 2][1], srcB);
        unsigned b3 = __shfl((int)pd[ks * 2 + 1][1], srcB);
        u32x4 pw;
        pw[0] = hiC ? b0 : a0;
        pw[1] = hiC ? b1 : a1;
        pw[2] = hiC ? b2 : a2;
        pw[3] = hiC ? b3 : a3;
        bf16x8 pf2 = __builtin_bit_cast(bf16x8, pw);
        bf16x8 vf[4];
#pragma unroll
        for (int g = 0; g < 4; ++g) {
          int erow = g * 16 + lrow;
          vf[g] = *(const bf16x8*)&Vs[cur][erow * 64 + (((ks * 4 + kk) ^ (erow & 7)) * 8)];
        }
        __builtin_amdgcn_s_setprio(1);
#pragma unroll
        for (int g = 0; g < 4; ++g)
          o_acc[g] = __builtin_amdgcn_mfma_f32_16x16x32_bf16(pf2, vf[g], o_acc[g], 0, 0, 0);
        __builtin_amdgcn_s_setprio(0);
      }
    }

    __syncthreads();                          // drain prefetch + swap
    cur ^= 1;
  }

  // ---- epilogue: 2-shuffle l reduce ----
  float l = rs_acc;
  l += __shfl_xor(l, 16);
  l += __shfl_xor(l, 32);

  if (!split) {
    float inv_[4];
#pragma unroll
    for (int r = 0; r < 4; ++r) inv_[r] = 1.f / __shfl(l, kk * 4 + r);
#pragma unroll
    for (int g = 0; g < 4; ++g)
#pragma unroll
      for (int r = 0; r < 4; ++r) {
        int s_idx = qw + kk * 4 + r;
        O[(size_t)s_idx * 1024 + h * 64 + g * 16 + lrow] =
            f2bf(o_acc[g][r] * inv_[r]);
      }
  } else {
    const int pidx = (h * 32 + qtile) * 2 + sp;
    float* op = opart + (size_t)pidx * 8192;  // [128 q][64 d]
    float* lp = lpart + pidx * 128;
    if (lane < 16) lp[w * 16 + lrow] = l;
#pragma unroll
    for (int g = 0; g < 4; ++g)
#pragma unroll
      for (int r = 0; r < 4; ++r)
        op[(w * 16 + kk * 4 + r) * 64 + g * 16 + lrow] = o_acc[g][r];
  }
}

// combine (split qtiles 16..31 only): attn_o[srow][col] = bf16( (o0+o1) / (l0+l1) )
__global__ __launch_bounds__(256) void attn_combine_kernel(
    const float* __restrict__ opart, const float* __restrict__ lpart,
    short* __restrict__ O) {
  size_t e8 = ((size_t)blockIdx.x * 256 + threadIdx.x) * 8 + (size_t)2048 * 1024;
  const int srow = (int)(e8 >> 10);
  const int col = (int)(e8 & 1023);
  const int h = col >> 6, d = col & 63;
  const int qtile = srow >> 7, qr = srow & 127;
  const int pb = (h * 32 + qtile) * 2;
  const float* o0 = opart + (size_t)pb * 8192 + qr * 64 + d;
  const float* o1 = opart + (size_t)(pb + 1) * 8192 + qr * 64 + d;
  float l = lpart[pb * 128 + qr] + lpart[(pb + 1) * 128 + qr];
  float4 a0 = *(const float4*)o0;
  float4 a1 = *(const float4*)(o0 + 4);
  float4 b0 = *(const float4*)o1;
  float4 b1 = *(const float4*)(o1 + 4);
  a0.x += b0.x; a0.y += b0.y; a0.z += b0.z; a0.w += b0.w;
  a1.x += b1.x; a1.y += b1.y; a1.z += b1.z; a1.w += b1.w;
  float inv = 1.f / l;
  bf16x8 o;
  o[0] = f2bf(a0.x * inv); o[1] = f2bf(a0.y * inv);
  o[2] = f2bf(a0.z * inv); o[3] = f2bf(a0.w * inv);
  o[4] = f2bf(a1.x * inv); o[5] = f2bf(a1.y * inv);
  o[6] = f2bf(a1.z * inv); o[7] = f2bf(a1.w * inv);
  *(bf16x8*)&O[e8] = o;
}

// ---------------- launch ----------------
extern "C" void kernel_launch(void* const* d_in, const int* in_sizes, int n_in,
                              void* d_out, int out_size, void* d_ws, size_t ws_size,
                              hipStream_t stream) {
  const float* x  = (const float*)d_in[0];
  const float* g1 = (const float*)d_in[2];
  const float* WQ = (const float*)d_in[3];
  const float* WK = (const float*)d_in[4];
  const float* WV = (const float*)d_in[5];
  const float* WO = (const float*)d_in[6];
  const float* g2 = (const float*)d_in[7];
  const float* W1 = (const float*)d_in[8];
  const float* B1 = (const float*)d_in[9];
  const float* W2 = (const float*)d_in[10];
  const float* B2 = (const float*)d_in[11];
  float* out = (float*)d_out;

  const int S = 4096, D = 1024, H = 16;

  char* ws = (char*)d_ws;
  size_t off = 0;
  auto alloc = [&](size_t bytes) -> void* {
    void* p = ws + off;
    off += (bytes + 255) & ~(size_t)255;
    return p;
  };
  short* h1     = (short*)alloc((size_t)S * D * 2);
  short* wqkv_t = (short*)alloc((size_t)3072 * 1024 * 2);
  short* qkv    = (short*)alloc((size_t)S * 3072 * 2);   // fused QKV output
  short* vt     = (short*)alloc((size_t)1024 * S * 2);
  short* attn_o = (short*)alloc((size_t)S * D * 2);
  short* wo_t   = (short*)alloc((size_t)1024 * 1024 * 2);
  float* x2     = (float*)alloc((size_t)S * D * 4);
  short* h2     = (short*)alloc((size_t)S * D * 2);
  short* w1_t   = (short*)alloc((size_t)4096 * 1024 * 2);
  short* m1     = (short*)alloc((size_t)S * 4096 * 2);
  short* w2_t   = (short*)alloc((size_t)1024 * 4096 * 2);
  short* partW2 = qkv;         // W2 split-K partials (33.55MB) alias qkv(25.2)+vt(8.4) (dead by then)
  float* opart  = (float*)m1;  // attn o-partials (split qtiles only): aliases m1 (dead until W1)
  float* lpart  = (float*)h1;  // attn l-partials: 512KB (h1 dead after QKV gemm)

  // merged weight prep + rmsnorm1, one dispatch
  prep_kernel<<<dim3(3072 + S), 256, 0, stream>>>(WQ, WK, WV, wqkv_t,
                                                  WO, wo_t, W1, w1_t, W2, w2_t,
                                                  x, g1, h1);

  // attention sub-block
  gemm256_kernel<0><<<dim3(3072 / 256, S / 256, 1), 512, 0, stream>>>(
      h1, wqkv_t, 3072, 1024, 1024, 0, qkv, nullptr);
  transpose_v_kernel<<<dim3(S / 64, 1024 / 64), 256, 0, stream>>>(qkv, vt, S);
  attn_kernel<<<dim3(768), 512, 0, stream>>>(qkv, vt, opart, lpart, attn_o);
  attn_combine_kernel<<<dim3((2048 * 1024 / 8) / 256), 256, 0, stream>>>(opart, lpart, attn_o);
  // WO: 128x64 tiles -> 512 blocks, 2 blocks/CU
  gemm_bt64_kernel<<<dim3(1024 / 64, S / 128), 256, 0, stream>>>(
      attn_o, wo_t, S, 1024, 1024, x2, x);

  // MLP sub-block
  rmsnorm_kernel<<<S, 256, 0, stream>>>(x2, g2, h2, D);
  gemm256_kernel<2><<<dim3(4096 / 256, 4096 / 256, 1), 512, 0, stream>>>(
      h2, w1_t, 4096, 1024, 1024, 0, m1, B1);
  gemm256_kernel<0><<<dim3(1024 / 256, 4096 / 256, 4), 512, 0, stream>>>(
      m1, w2_t, 1024, 4096, 1024, (size_t)4096 * 1024, partW2, nullptr);
  reduce4_kernel<<<2048, 256, 0, stream>>>(partW2, B2, x2, out);
}

// Round 16
// 230.010 us; speedup vs baseline: 1.1010x; 1.1010x over previous
//
#include <hip/hip_runtime.h>
#include <hip/hip_bf16.h>

typedef __attribute__((ext_vector_type(8))) short bf16x8;
typedef __attribute__((ext_vector_type(4))) float f32x4;
typedef __attribute__((ext_vector_type(4))) short s16x4;

#define GLOBAL_AS(p) ((const __attribute__((address_space(1))) void*)(p))
#define LDS_AS(p)    ((__attribute__((address_space(3))) void*)(p))

__device__ __forceinline__ short f2bf(float f) {
  return __builtin_bit_cast(short, __float2bfloat16(f));   // HW RNE cvt
}
__device__ __forceinline__ float bf2f(short s) {
  return __bfloat162float(__builtin_bit_cast(__hip_bfloat16, s));
}

// ---------------- merged weight prep + rmsnorm1 (one dispatch) ----------------
// bid 0..767: pack WQ/WK/WV; 768..1023: WO^T; 1024..2047: W1^T; 2048..3071: W2^T
// bid 3072..7167: rmsnorm row (bid-3072) of x -> h1
__global__ __launch_bounds__(256) void prep_kernel(
    const float* __restrict__ WQ, const float* __restrict__ WK,
    const float* __restrict__ WV, short* __restrict__ wqkv_t,
    const float* __restrict__ WO, short* __restrict__ wo_t,
    const float* __restrict__ W1, short* __restrict__ w1_t,
    const float* __restrict__ W2, short* __restrict__ w2_t,
    const float* __restrict__ x, const float* __restrict__ g1,
    short* __restrict__ h1) {
  __shared__ short Ls[64][66];
  __shared__ float red[4];
  const int tid = threadIdx.x;
  const int l = tid & 63, q4 = tid >> 6;
  const int bid = blockIdx.x;

  if (bid >= 3072) {
    const int row = bid - 3072;
    const float4 xv = *(const float4*)&x[(size_t)row * 1024 + tid * 4];
    float ss = xv.x * xv.x + xv.y * xv.y + xv.z * xv.z + xv.w * xv.w;
#pragma unroll
    for (int off = 32; off; off >>= 1) ss += __shfl_xor(ss, off);
    if ((tid & 63) == 0) red[tid >> 6] = ss;
    __syncthreads();
    float tot = red[0] + red[1] + red[2] + red[3];
    float scale = rsqrtf(tot / 1024.f + 1e-6f);
    const float4 gv = *(const float4*)&g1[tid * 4];
    s16x4 o;
    o[0] = f2bf(xv.x * scale * gv.x);
    o[1] = f2bf(xv.y * scale * gv.y);
    o[2] = f2bf(xv.z * scale * gv.z);
    o[3] = f2bf(xv.w * scale * gv.w);
    *(s16x4*)&h1[(size_t)row * 1024 + tid * 4] = o;
    return;
  }

  if (bid < 768) {
    const int xb = bid & 15, y = bid >> 4;
    const int hh = y & 15, proj = y >> 4;
    const float* W = (proj == 0) ? WQ : ((proj == 1) ? WK : WV);
    const float scl = (proj == 0) ? 0.125f : 1.f;
    const int d0 = xb * 64;
#pragma unroll
    for (int rep = 0; rep < 16; ++rep) {
      int dd = q4 * 16 + rep;
      Ls[dd][l] = f2bf(W[(size_t)hh * 65536 + (size_t)(d0 + dd) * 64 + l] * scl);
    }
    __syncthreads();
#pragma unroll
    for (int rep = 0; rep < 16; ++rep) {
      int ee = q4 * 16 + rep;
      wqkv_t[(size_t)(proj * 1024 + hh * 64 + ee) * 1024 + d0 + l] = Ls[l][ee];
    }
  } else {
    const float* in; short* out; int R, C, bx, by;
    if (bid < 1024) {
      int idx = bid - 768;  in = WO; out = wo_t; R = 1024; C = 1024;
      bx = idx & 15; by = idx >> 4;
    } else if (bid < 2048) {
      int idx = bid - 1024; in = W1; out = w1_t; R = 1024; C = 4096;
      bx = idx & 63; by = idx >> 6;
    } else {
      int idx = bid - 2048; in = W2; out = w2_t; R = 4096; C = 1024;
      bx = idx & 15; by = idx >> 4;
    }
    const int c0 = bx * 64, r0 = by * 64;
#pragma unroll
    for (int rep = 0; rep < 16; ++rep) {
      int rr = q4 * 16 + rep;
      Ls[rr][l] = f2bf(in[(size_t)(r0 + rr) * C + c0 + l]);
    }
    __syncthreads();
#pragma unroll
    for (int rep = 0; rep < 16; ++rep) {
      int cc = q4 * 16 + rep;
      out[(size_t)(c0 + cc) * R + r0 + l] = Ls[l][cc];
    }
  }
}

// V columns of qkv [S][3072] (cols 2048..3071) -> vt [1024][S], bf16->bf16
__global__ __launch_bounds__(256) void transpose_v_kernel(
    const short* __restrict__ qkv, short* __restrict__ vt, int S) {
  __shared__ short Ls[64][66];
  const int tid = threadIdx.x;
  const int l = tid & 63, q4 = tid >> 6;
  const int s0 = blockIdx.x * 64, e0 = blockIdx.y * 64;
#pragma unroll
  for (int rep = 0; rep < 16; ++rep) {
    int rr = q4 * 16 + rep;
    Ls[rr][l] = qkv[(size_t)(s0 + rr) * 3072 + 2048 + e0 + l];
  }
  __syncthreads();
#pragma unroll
  for (int rep = 0; rep < 16; ++rep) {
    int ee = q4 * 16 + rep;
    vt[(size_t)(e0 + ee) * S + s0 + l] = Ls[l][ee];
  }
}

// ---------------- RMSNorm (fp32 in -> bf16 out) ----------------
__global__ __launch_bounds__(256) void rmsnorm_kernel(
    const float* __restrict__ x, const float* __restrict__ g,
    short* __restrict__ out, int D) {
  const int row = blockIdx.x;
  const int tid = threadIdx.x;
  const float4 xv = *(const float4*)&x[(size_t)row * D + tid * 4];
  float ss = xv.x * xv.x + xv.y * xv.y + xv.z * xv.z + xv.w * xv.w;
#pragma unroll
  for (int off = 32; off; off >>= 1) ss += __shfl_xor(ss, off);
  __shared__ float red[4];
  if ((tid & 63) == 0) red[tid >> 6] = ss;
  __syncthreads();
  float tot = red[0] + red[1] + red[2] + red[3];
  float scale = rsqrtf(tot / (float)D + 1e-6f);
  const float4 gv = *(const float4*)&g[tid * 4];
  s16x4 o;
  o[0] = f2bf(xv.x * scale * gv.x);
  o[1] = f2bf(xv.y * scale * gv.y);
  o[2] = f2bf(xv.z * scale * gv.z);
  o[3] = f2bf(xv.w * scale * gv.w);
  *(s16x4*)&out[(size_t)row * D + tid * 4] = o;
}

// ---------------- 128x64 GEMM (WO): C = A[M,K] x BT[N,K]^T, fp32 out + addend ----------------
__global__ __launch_bounds__(256) void gemm_bt64_kernel(
    const short* __restrict__ A, const short* __restrict__ BT,
    int M, int N, int K,
    float* __restrict__ outF, const float* __restrict__ addend) {
  __shared__ short As[128 * 32];
  __shared__ short Bs[64 * 32];
  const int tid = threadIdx.x;
  const int lane = tid & 63;
  const int wid = tid >> 6;
  const int lrow = lane & 15;
  const int kk = lane >> 4;
  const int row0 = blockIdx.y * 128;
  const int col0 = blockIdx.x * 64;
  const int wm = wid >> 1, wn = wid & 1;

  f32x4 acc[4][2] = {};

  for (int k0 = 0; k0 < K; k0 += 32) {
    __syncthreads();
#pragma unroll
    for (int it = 0; it < 2; ++it) {
      int c = it * 256 + tid;
      int r = c >> 2, c8 = (c & 3) * 8;
      const short* ga = A + (size_t)(row0 + r) * K + k0 + c8;
      short* la = &As[(size_t)(it * 256 + wid * 64) * 8];
      __builtin_amdgcn_global_load_lds(GLOBAL_AS(ga), LDS_AS(la), 16, 0, 0);
    }
    {
      int r = tid >> 2, c8 = (tid & 3) * 8;
      const short* gb = BT + (size_t)(col0 + r) * K + k0 + c8;
      short* lb = &Bs[(size_t)(wid * 64) * 8];
      __builtin_amdgcn_global_load_lds(GLOBAL_AS(gb), LDS_AS(lb), 16, 0, 0);
    }
    __syncthreads();

    bf16x8 a[4], b[2];
#pragma unroll
    for (int i = 0; i < 4; ++i)
      a[i] = *(const bf16x8*)&As[(wm * 64 + i * 16 + lrow) * 32 + kk * 8];
#pragma unroll
    for (int j = 0; j < 2; ++j)
      b[j] = *(const bf16x8*)&Bs[(wn * 32 + j * 16 + lrow) * 32 + kk * 8];
#pragma unroll
    for (int i = 0; i < 4; ++i)
#pragma unroll
      for (int j = 0; j < 2; ++j)
        acc[i][j] = __builtin_amdgcn_mfma_f32_16x16x32_bf16(a[i], b[j], acc[i][j], 0, 0, 0);
  }

#pragma unroll
  for (int i = 0; i < 4; ++i) {
    int row = row0 + wm * 64 + i * 16 + kk * 4;
#pragma unroll
    for (int j = 0; j < 2; ++j) {
      int col = col0 + wn * 32 + j * 16 + lrow;
#pragma unroll
      for (int r = 0; r < 4; ++r) {
        size_t o = (size_t)(row + r) * N + col;
        outF[o] = acc[i][j][r] + addend[o];
      }
    }
  }
}

// ---------------- 256x256 8-phase GEMM (T2+T3+T4+T5), bf16 out ----------------
#define READ_A(buf, mh)                                                      \
  _Pragma("unroll") for (int m4 = 0; m4 < 4; ++m4) {                         \
    int row_ = wm * 128 + ((mh)*4 + m4) * 16 + lrow;                         \
    _Pragma("unroll") for (int k_ = 0; k_ < 2; ++k_) {                       \
      int sl_ = (k_ * 4 + kk) ^ (row_ & 7);                                  \
      aA[m4][k_] = *(const bf16x8*)&lds[buf][0][row_ * 64 + sl_ * 8];        \
    }                                                                        \
  }
#define READ_B2(buf, pr)                                                     \
  _Pragma("unroll") for (int nn = 0; nn < 2; ++nn) {                         \
    int n_ = (pr)*2 + nn;                                                    \
    int row_ = wn * 64 + n_ * 16 + lrow;                                     \
    _Pragma("unroll") for (int k_ = 0; k_ < 2; ++k_) {                       \
      int sl_ = (k_ * 4 + kk) ^ (row_ & 7);                                  \
      bB[n_][k_] = *(const bf16x8*)&lds[buf][1][row_ * 64 + sl_ * 8];        \
    }                                                                        \
  }
#define MFMA16(mh, nh)                                                       \
  _Pragma("unroll") for (int m4 = 0; m4 < 4; ++m4)                           \
  _Pragma("unroll") for (int n2 = 0; n2 < 2; ++n2)                           \
  _Pragma("unroll") for (int k_ = 0; k_ < 2; ++k_)                           \
    acc[(mh)*4 + m4][(nh)*2 + n2] = __builtin_amdgcn_mfma_f32_16x16x32_bf16( \
        aA[m4][k_], bB[(nh)*2 + n2][k_], acc[(mh)*4 + m4][(nh)*2 + n2], 0, 0, 0);
#define STAGE_HALF(buf, mat, half, kt)                                       \
  {                                                                          \
    const short* g_ = ((mat) ? Bb : Ab) + (size_t)((half)*128) * K + (kt)*64;\
    short* l_ = &lds[buf][mat][(half)*8192];                                 \
    _Pragma("unroll") for (int it_ = 0; it_ < 2; ++it_) {                    \
      int ci_ = it_ * 512 + tid;                                             \
      int r_ = ci_ >> 3, sl_ = (ci_ & 7) ^ (r_ & 7);                         \
      __builtin_amdgcn_global_load_lds(GLOBAL_AS(g_ + (size_t)r_ * K + sl_ * 8), \
                                       LDS_AS(l_ + ci_ * 8), 16, 0, 0);      \
    }                                                                        \
  }
#define PH_SYNC1()                                                           \
  __builtin_amdgcn_s_barrier();                                              \
  asm volatile("s_waitcnt lgkmcnt(0)" ::: "memory");                         \
  __builtin_amdgcn_sched_barrier(0);                                         \
  __builtin_amdgcn_s_setprio(1)
#define PH_SYNC2()                                                           \
  __builtin_amdgcn_s_setprio(0);                                             \
  __builtin_amdgcn_s_barrier()
#define PH_SYNC2_VM(n)                                                       \
  __builtin_amdgcn_s_setprio(0);                                             \
  asm volatile("s_waitcnt vmcnt(" #n ")" ::: "memory");                      \
  __builtin_amdgcn_s_barrier()

template <int EPI>
__global__ __launch_bounds__(512, 2) void gemm256_kernel(
    const short* __restrict__ A, const short* __restrict__ BT,
    int N, int K, int kslice, size_t pstride,
    short* __restrict__ outB, const float* __restrict__ bias) {
  __shared__ short lds[2][2][16384];   // [buf][A/B][256 rows x 64 k], 128 KiB
  const int tid = threadIdx.x;
  const int lane = tid & 63, wid = tid >> 6;
  const int lrow = lane & 15, kk = lane >> 4;
  const int wm = wid >> 2, wn = wid & 3;
  const int row0 = blockIdx.y * 256, col0 = blockIdx.x * 256;
  const int kbase = blockIdx.z * kslice;
  const int NT = kslice >> 6;

  const short* Ab = A + (size_t)row0 * K + kbase;
  const short* Bb = BT + (size_t)col0 * K + kbase;

  f32x4 acc[8][4] = {};
  bf16x8 aA[4][2], bB[4][2];

  STAGE_HALF(0, 1, 0, 0); STAGE_HALF(0, 0, 0, 0);
  STAGE_HALF(0, 1, 1, 0); STAGE_HALF(0, 0, 1, 0);
  STAGE_HALF(1, 1, 0, 1); STAGE_HALF(1, 0, 0, 1); STAGE_HALF(1, 0, 1, 1);
  asm volatile("s_waitcnt vmcnt(6)" ::: "memory");
  __builtin_amdgcn_s_barrier();

  const int iters = NT >> 1;
  for (int i = 0; i < iters; ++i) {
    const int t1 = 2 * i + 1;
    int kt2 = 2 * i + 2; if (kt2 >= NT) kt2 -= NT;
    int kt3 = 2 * i + 3; if (kt3 >= NT) kt3 -= NT;
    READ_A(0, 0); READ_B2(0, 0); STAGE_HALF(1, 1, 1, t1);
    PH_SYNC1(); MFMA16(0, 0); PH_SYNC2();
    READ_B2(0, 1);
    PH_SYNC1(); MFMA16(0, 1); PH_SYNC2();
    READ_A(0, 1); STAGE_HALF(0, 1, 0, kt2);
    PH_SYNC1(); MFMA16(1, 0); PH_SYNC2();
    STAGE_HALF(0, 0, 0, kt2);
    PH_SYNC1(); MFMA16(1, 1); PH_SYNC2_VM(4);
    READ_A(1, 0); READ_B2(1, 0); STAGE_HALF(0, 1, 1, kt2);
    PH_SYNC1(); MFMA16(0, 0); PH_SYNC2();
    READ_B2(1, 1); STAGE_HALF(0, 0, 1, kt2);
    PH_SYNC1(); MFMA16(0, 1); PH_SYNC2();
    READ_A(1, 1); STAGE_HALF(1, 1, 0, kt3);
    PH_SYNC1(); MFMA16(1, 0); PH_SYNC2();
    STAGE_HALF(1, 0, 0, kt3); STAGE_HALF(1, 0, 1, kt3);
    PH_SYNC1(); MFMA16(1, 1); PH_SYNC2_VM(6);
  }

  short* ob = outB + (size_t)blockIdx.z * pstride;
#pragma unroll
  for (int m = 0; m < 8; ++m) {
    int row = row0 + wm * 128 + m * 16 + kk * 4;
#pragma unroll
    for (int n = 0; n < 4; ++n) {
      int col = col0 + wn * 64 + n * 16 + lrow;
#pragma unroll
      for (int r = 0; r < 4; ++r) {
        float v = acc[m][n][r];
        size_t o = (size_t)(row + r) * N + col;
        if (EPI == 0) {
          ob[o] = f2bf(v);
        } else {
          v += bias[col];
          ob[o] = f2bf(v > 0.f ? v : 0.f);
        }
      }
    }
  }
}

// out[i] = sum_{s<4} part[s][i] + bias[i % 1024] + addend[i]   (W2 split-K reduce)
__global__ __launch_bounds__(256) void reduce4_kernel(
    const short* __restrict__ part, const float* __restrict__ bias,
    const float* __restrict__ addend, float* __restrict__ out) {
  const size_t MN = (size_t)4096 * 1024;
  size_t i8 = ((size_t)blockIdx.x * 256 + threadIdx.x) * 8;
  bf16x8 p0 = *(const bf16x8*)&part[i8];
  bf16x8 p1 = *(const bf16x8*)&part[MN + i8];
  bf16x8 p2 = *(const bf16x8*)&part[2 * MN + i8];
  bf16x8 p3 = *(const bf16x8*)&part[3 * MN + i8];
  int col = (int)(i8 & 1023);
#pragma unroll
  for (int j = 0; j < 8; ++j) {
    float v = (bf2f(p0[j]) + bf2f(p1[j])) + (bf2f(p2[j]) + bf2f(p3[j]));
    out[i8 + j] = v + bias[col + j] + addend[i8 + j];
  }
}

// ---------------- flash attention v12 (round-14 proven): KVBLK=64, 3 blocks/CU ----------------
// LDS 48KB (Ks/Vs dbuf 64x64 + per-wave Ps) -> 3 blocks/CU = 24 waves/CU.
// Swapped QK^T + packed b64 P stores. (v13 in-register P spilled at the
// (512,8) VGPR budget: WRITE_SIZE 25->74MB scratch, attn 57->90us. Reverted.)
__device__ const unsigned char QT_SLOT[48] = {
    31, 31, 30, 15, 30, 29, 29, 28, 14, 28, 27, 27, 26, 13, 26, 25,
    25, 24, 12, 24, 23, 23, 22, 11, 22, 21, 21, 20, 10, 20, 19, 19,
    18,  9, 18, 17, 17, 16,  8, 16,  7,  6,  5,  4,  3,  2,  1,  0};
__device__ const unsigned char SP_SLOT[48] = {
    0, 1, 0, 0, 1, 0, 1, 0, 0, 1, 0, 1, 0, 0, 1, 0,
    1, 0, 0, 1, 0, 1, 0, 0, 1, 0, 1, 0, 0, 1, 0, 1,
    0, 0, 1, 0, 1, 0, 0, 1, 0, 0, 0, 0, 0, 0, 0, 0};

__global__ __launch_bounds__(512, 6) void attn_kernel(
    const short* __restrict__ QKV, const short* __restrict__ VT,
    float* __restrict__ opart, float* __restrict__ lpart,
    short* __restrict__ O) {
  const int S = 4096;
  __shared__ short Ks[2][64 * 64];
  __shared__ short Vs[2][64 * 64];
  __shared__ short Ps[8][16 * 64];

  const int tid = threadIdx.x;
  const int lane = tid & 63;
  const int w = tid >> 6;                     // 0..7
  const int lrow = lane & 15;
  const int kk = lane >> 4;
  const int bid = blockIdx.x;
  const int h = bid & 15;
  const int slot = bid >> 4;
  const int qtile = QT_SLOT[slot];
  const int sp = SP_SLOT[slot];
  const int T = 2 * qtile + 2;                // total 64-key tiles for this qtile
  const bool split = (qtile >= 16);
  const int half = qtile + 1;
  const int t0 = (split && sp) ? half : 0;
  const int t1 = (split && !sp) ? half : T;
  const int q0 = qtile * 128;
  const int qw = q0 + w * 16;                 // 16 q-rows per wave
  const int myq = qw + lrow;                  // this lane's q row (swapped layout)

  auto stage = [&](int buf, int t) {
    const int kv0 = t * 64;
    int krow = tid >> 3;                      // 64 rows x 8 slots
    int ksl = (tid & 7) ^ (krow & 7);
    const short* gk = QKV + (size_t)(kv0 + krow) * 3072 + 1024 + h * 64 + ksl * 8;
    const short* gv = VT + (size_t)(h * 64 + krow) * S + kv0 + ksl * 8;
    __builtin_amdgcn_global_load_lds(GLOBAL_AS(gk),
                                     LDS_AS(&Ks[buf][(w * 64) * 8]), 16, 0, 0);
    __builtin_amdgcn_global_load_lds(GLOBAL_AS(gv),
                                     LDS_AS(&Vs[buf][(w * 64) * 8]), 16, 0, 0);
  };

  bf16x8 qf[2];
#pragma unroll
  for (int half2 = 0; half2 < 2; ++half2)
    qf[half2] = *(const bf16x8*)&QKV[(size_t)(qw + lrow) * 3072 +
                                     h * 64 + half2 * 32 + kk * 8];

  float rs_acc = 0.f;
  f32x4 o_acc[4] = {};

  stage(0, t0);
  __syncthreads();
  int cur = 0;

  for (int t = t0; t < t1; ++t) {
    if (t + 1 < t1) stage(cur ^ 1, t + 1);    // prefetch next 64-key tile

    const int kvc = t * 64;
    if (kvc <= qw + 15) {
      // ---- QK^T (swapped): sc[c] row=key(kk*4+r), col=q(lrow) ----
      bf16x8 kf[4][2];
#pragma unroll
      for (int c = 0; c < 4; ++c)
#pragma unroll
        for (int half2 = 0; half2 < 2; ++half2) {
          int krow = c * 16 + lrow;
          kf[c][half2] = *(const bf16x8*)&Ks[cur][krow * 64 + (((half2 * 4 + kk) ^ (krow & 7)) * 8)];
        }
      f32x4 sc[4];
      __builtin_amdgcn_s_setprio(1);
#pragma unroll
      for (int c = 0; c < 4; ++c) {
        f32x4 z = {};
        z = __builtin_amdgcn_mfma_f32_16x16x32_bf16(kf[c][0], qf[0], z, 0, 0, 0);
        z = __builtin_amdgcn_mfma_f32_16x16x32_bf16(kf[c][1], qf[1], z, 0, 0, 0);
        sc[c] = z;
      }
      __builtin_amdgcn_s_setprio(0);

      // ---- softmax numerator: lane holds 4 consecutive keys for q=myq ----
      if (kvc + 63 <= qw) {
#pragma unroll
        for (int c = 0; c < 4; ++c) {
          float p0 = __expf(sc[c][0]), p1 = __expf(sc[c][1]);
          float p2 = __expf(sc[c][2]), p3 = __expf(sc[c][3]);
          rs_acc += (p0 + p1) + (p2 + p3);
          s16x4 pk;
          pk[0] = f2bf(p0); pk[1] = f2bf(p1); pk[2] = f2bf(p2); pk[3] = f2bf(p3);
          int slot8 = c * 2 + (kk >> 1);
          *(s16x4*)&Ps[w][lrow * 64 + ((slot8 ^ (lrow & 7)) * 8) + (kk & 1) * 4] = pk;
        }
      } else {
#pragma unroll
        for (int c = 0; c < 4; ++c) {
          const int keyb = kvc + c * 16 + kk * 4;
          float pv[4];
#pragma unroll
          for (int r = 0; r < 4; ++r) {
            float p = __expf(sc[c][r]);
            if (keyb + r > myq) p = 0.f;
            pv[r] = p;
          }
          rs_acc += (pv[0] + pv[1]) + (pv[2] + pv[3]);
          s16x4 pk;
          pk[0] = f2bf(pv[0]); pk[1] = f2bf(pv[1]); pk[2] = f2bf(pv[2]); pk[3] = f2bf(pv[3]);
          int slot8 = c * 2 + (kk >> 1);
          *(s16x4*)&Ps[w][lrow * 64 + ((slot8 ^ (lrow & 7)) * 8) + (kk & 1) * 4] = pk;
        }
      }

      // ---- PV over this chunk (8 MFMA) ----
#pragma unroll
      for (int ks = 0; ks < 2; ++ks) {
        bf16x8 pf2, vf[4];
        {
          int qrow = lrow;
          pf2 = *(const bf16x8*)&Ps[w][qrow * 64 + (((ks * 4 + kk) ^ (qrow & 7)) * 8)];
        }
#pragma unroll
        for (int g = 0; g < 4; ++g) {
          int erow = g * 16 + lrow;
          vf[g] = *(const bf16x8*)&Vs[cur][erow * 64 + (((ks * 4 + kk) ^ (erow & 7)) * 8)];
        }
        __builtin_amdgcn_s_setprio(1);
#pragma unroll
        for (int g = 0; g < 4; ++g)
          o_acc[g] = __builtin_amdgcn_mfma_f32_16x16x32_bf16(pf2, vf[g], o_acc[g], 0, 0, 0);
        __builtin_amdgcn_s_setprio(0);
      }
    }

    __syncthreads();                          // drain prefetch + swap
    cur ^= 1;
  }

  // ---- epilogue: 2-shuffle l reduce ----
  float l = rs_acc;
  l += __shfl_xor(l, 16);
  l += __shfl_xor(l, 32);

  if (!split) {
    float inv_[4];
#pragma unroll
    for (int r = 0; r < 4; ++r) inv_[r] = 1.f / __shfl(l, kk * 4 + r);
#pragma unroll
    for (int g = 0; g < 4; ++g)
#pragma unroll
      for (int r = 0; r < 4; ++r) {
        int s_idx = qw + kk * 4 + r;
        O[(size_t)s_idx * 1024 + h * 64 + g * 16 + lrow] =
            f2bf(o_acc[g][r] * inv_[r]);
      }
  } else {
    const int pidx = (h * 32 + qtile) * 2 + sp;
    float* op = opart + (size_t)pidx * 8192;  // [128 q][64 d]
    float* lp = lpart + pidx * 128;
    if (lane < 16) lp[w * 16 + lrow] = l;
#pragma unroll
    for (int g = 0; g < 4; ++g)
#pragma unroll
      for (int r = 0; r < 4; ++r)
        op[(w * 16 + kk * 4 + r) * 64 + g * 16 + lrow] = o_acc[g][r];
  }
}

// combine (split qtiles 16..31 only): attn_o[srow][col] = bf16( (o0+o1) / (l0+l1) )
__global__ __launch_bounds__(256) void attn_combine_kernel(
    const float* __restrict__ opart, const float* __restrict__ lpart,
    short* __restrict__ O) {
  size_t e8 = ((size_t)blockIdx.x * 256 + threadIdx.x) * 8 + (size_t)2048 * 1024;
  const int srow = (int)(e8 >> 10);
  const int col = (int)(e8 & 1023);
  const int h = col >> 6, d = col & 63;
  const int qtile = srow >> 7, qr = srow & 127;
  const int pb = (h * 32 + qtile) * 2;
  const float* o0 = opart + (size_t)pb * 8192 + qr * 64 + d;
  const float* o1 = opart + (size_t)(pb + 1) * 8192 + qr * 64 + d;
  float l = lpart[pb * 128 + qr] + lpart[(pb + 1) * 128 + qr];
  float4 a0 = *(const float4*)o0;
  float4 a1 = *(const float4*)(o0 + 4);
  float4 b0 = *(const float4*)o1;
  float4 b1 = *(const float4*)(o1 + 4);
  a0.x += b0.x; a0.y += b0.y; a0.z += b0.z; a0.w += b0.w;
  a1.x += b1.x; a1.y += b1.y; a1.z += b1.z; a1.w += b1.w;
  float inv = 1.f / l;
  bf16x8 o;
  o[0] = f2bf(a0.x * inv); o[1] = f2bf(a0.y * inv);
  o[2] = f2bf(a0.z * inv); o[3] = f2bf(a0.w * inv);
  o[4] = f2bf(a1.x * inv); o[5] = f2bf(a1.y * inv);
  o[6] = f2bf(a1.z * inv); o[7] = f2bf(a1.w * inv);
  *(bf16x8*)&O[e8] = o;
}

// ---------------- launch ----------------
extern "C" void kernel_launch(void* const* d_in, const int* in_sizes, int n_in,
                              void* d_out, int out_size, void* d_ws, size_t ws_size,
                              hipStream_t stream) {
  const float* x  = (const float*)d_in[0];
  const float* g1 = (const float*)d_in[2];
  const float* WQ = (const float*)d_in[3];
  const float* WK = (const float*)d_in[4];
  const float* WV = (const float*)d_in[5];
  const float* WO = (const float*)d_in[6];
  const float* g2 = (const float*)d_in[7];
  const float* W1 = (const float*)d_in[8];
  const float* B1 = (const float*)d_in[9];
  const float* W2 = (const float*)d_in[10];
  const float* B2 = (const float*)d_in[11];
  float* out = (float*)d_out;

  const int S = 4096, D = 1024, H = 16;

  char* ws = (char*)d_ws;
  size_t off = 0;
  auto alloc = [&](size_t bytes) -> void* {
    void* p = ws + off;
    off += (bytes + 255) & ~(size_t)255;
    return p;
  };
  short* h1     = (short*)alloc((size_t)S * D * 2);
  short* wqkv_t = (short*)alloc((size_t)3072 * 1024 * 2);
  short* qkv    = (short*)alloc((size_t)S * 3072 * 2);   // fused QKV output
  short* vt     = (short*)alloc((size_t)1024 * S * 2);
  short* attn_o = (short*)alloc((size_t)S * D * 2);
  short* wo_t   = (short*)alloc((size_t)1024 * 1024 * 2);
  float* x2     = (float*)alloc((size_t)S * D * 4);
  short* h2     = (short*)alloc((size_t)S * D * 2);
  short* w1_t   = (short*)alloc((size_t)4096 * 1024 * 2);
  short* m1     = (short*)alloc((size_t)S * 4096 * 2);
  short* w2_t   = (short*)alloc((size_t)1024 * 4096 * 2);
  short* partW2 = qkv;         // W2 split-K partials (33.55MB) alias qkv(25.2)+vt(8.4) (dead by then)
  float* opart  = (float*)m1;  // attn o-partials (split qtiles only): aliases m1 (dead until W1)
  float* lpart  = (float*)h1;  // attn l-partials: 512KB (h1 dead after QKV gemm)

  // merged weight prep + rmsnorm1, one dispatch
  prep_kernel<<<dim3(3072 + S), 256, 0, stream>>>(WQ, WK, WV, wqkv_t,
                                                  WO, wo_t, W1, w1_t, W2, w2_t,
                                                  x, g1, h1);

  // attention sub-block
  gemm256_kernel<0><<<dim3(3072 / 256, S / 256, 1), 512, 0, stream>>>(
      h1, wqkv_t, 3072, 1024, 1024, 0, qkv, nullptr);
  transpose_v_kernel<<<dim3(S / 64, 1024 / 64), 256, 0, stream>>>(qkv, vt, S);
  attn_kernel<<<dim3(768), 512, 0, stream>>>(qkv, vt, opart, lpart, attn_o);
  attn_combine_kernel<<<dim3((2048 * 1024 / 8) / 256), 256, 0, stream>>>(opart, lpart, attn_o);
  // WO: 128x64 tiles -> 512 blocks, 2 blocks/CU
  gemm_bt64_kernel<<<dim3(1024 / 64, S / 128), 256, 0, stream>>>(
      attn_o, wo_t, S, 1024, 1024, x2, x);

  // MLP sub-block
  rmsnorm_kernel<<<S, 256, 0, stream>>>(x2, g2, h2, D);
  gemm256_kernel<2><<<dim3(4096 / 256, 4096 / 256, 1), 512, 0, stream>>>(
      h2, w1_t, 4096, 1024, 1024, 0, m1, B1);
  gemm256_kernel<0><<<dim3(1024 / 256, 4096 / 256, 4), 512, 0, stream>>>(
      m1, w2_t, 1024, 4096, 1024, (size_t)4096 * 1024, partW2, nullptr);
  reduce4_kernel<<<2048, 256, 0, stream>>>(partW2, B2, x2, out);
}

// Round 17
// 221.783 us; speedup vs baseline: 1.1418x; 1.0371x over previous
//
#include <hip/hip_runtime.h>
#include <hip/hip_bf16.h>

typedef __attribute__((ext_vector_type(8))) short bf16x8;
typedef __attribute__((ext_vector_type(4))) float f32x4;
typedef __attribute__((ext_vector_type(4))) short s16x4;

#define GLOBAL_AS(p) ((const __attribute__((address_space(1))) void*)(p))
#define LDS_AS(p)    ((__attribute__((address_space(3))) void*)(p))

__device__ __forceinline__ short f2bf(float f) {
  return __builtin_bit_cast(short, __float2bfloat16(f));   // HW RNE cvt
}
__device__ __forceinline__ float bf2f(short s) {
  return __bfloat162float(__builtin_bit_cast(__hip_bfloat16, s));
}

// ---------------- merged weight prep + rmsnorm1 (one dispatch) ----------------
__global__ __launch_bounds__(256) void prep_kernel(
    const float* __restrict__ WQ, const float* __restrict__ WK,
    const float* __restrict__ WV, short* __restrict__ wqkv_t,
    const float* __restrict__ WO, short* __restrict__ wo_t,
    const float* __restrict__ W1, short* __restrict__ w1_t,
    const float* __restrict__ W2, short* __restrict__ w2_t,
    const float* __restrict__ x, const float* __restrict__ g1,
    short* __restrict__ h1) {
  __shared__ short Ls[64][66];
  __shared__ float red[4];
  const int tid = threadIdx.x;
  const int l = tid & 63, q4 = tid >> 6;
  const int bid = blockIdx.x;

  if (bid >= 3072) {
    const int row = bid - 3072;
    const float4 xv = *(const float4*)&x[(size_t)row * 1024 + tid * 4];
    float ss = xv.x * xv.x + xv.y * xv.y + xv.z * xv.z + xv.w * xv.w;
#pragma unroll
    for (int off = 32; off; off >>= 1) ss += __shfl_xor(ss, off);
    if ((tid & 63) == 0) red[tid >> 6] = ss;
    __syncthreads();
    float tot = red[0] + red[1] + red[2] + red[3];
    float scale = rsqrtf(tot / 1024.f + 1e-6f);
    const float4 gv = *(const float4*)&g1[tid * 4];
    s16x4 o;
    o[0] = f2bf(xv.x * scale * gv.x);
    o[1] = f2bf(xv.y * scale * gv.y);
    o[2] = f2bf(xv.z * scale * gv.z);
    o[3] = f2bf(xv.w * scale * gv.w);
    *(s16x4*)&h1[(size_t)row * 1024 + tid * 4] = o;
    return;
  }

  if (bid < 768) {
    const int xb = bid & 15, y = bid >> 4;
    const int hh = y & 15, proj = y >> 4;
    const float* W = (proj == 0) ? WQ : ((proj == 1) ? WK : WV);
    const float scl = (proj == 0) ? 0.125f : 1.f;
    const int d0 = xb * 64;
#pragma unroll
    for (int rep = 0; rep < 16; ++rep) {
      int dd = q4 * 16 + rep;
      Ls[dd][l] = f2bf(W[(size_t)hh * 65536 + (size_t)(d0 + dd) * 64 + l] * scl);
    }
    __syncthreads();
#pragma unroll
    for (int rep = 0; rep < 16; ++rep) {
      int ee = q4 * 16 + rep;
      wqkv_t[(size_t)(proj * 1024 + hh * 64 + ee) * 1024 + d0 + l] = Ls[l][ee];
    }
  } else {
    const float* in; short* out; int R, C, bx, by;
    if (bid < 1024) {
      int idx = bid - 768;  in = WO; out = wo_t; R = 1024; C = 1024;
      bx = idx & 15; by = idx >> 4;
    } else if (bid < 2048) {
      int idx = bid - 1024; in = W1; out = w1_t; R = 1024; C = 4096;
      bx = idx & 63; by = idx >> 6;
    } else {
      int idx = bid - 2048; in = W2; out = w2_t; R = 4096; C = 1024;
      bx = idx & 15; by = idx >> 4;
    }
    const int c0 = bx * 64, r0 = by * 64;
#pragma unroll
    for (int rep = 0; rep < 16; ++rep) {
      int rr = q4 * 16 + rep;
      Ls[rr][l] = f2bf(in[(size_t)(r0 + rr) * C + c0 + l]);
    }
    __syncthreads();
#pragma unroll
    for (int rep = 0; rep < 16; ++rep) {
      int cc = q4 * 16 + rep;
      out[(size_t)(c0 + cc) * R + r0 + l] = Ls[l][cc];
    }
  }
}

// V columns of qkv [S][3072] (cols 2048..3071) -> vt [1024][S], bf16->bf16
__global__ __launch_bounds__(256) void transpose_v_kernel(
    const short* __restrict__ qkv, short* __restrict__ vt, int S) {
  __shared__ short Ls[64][66];
  const int tid = threadIdx.x;
  const int l = tid & 63, q4 = tid >> 6;
  const int s0 = blockIdx.x * 64, e0 = blockIdx.y * 64;
#pragma unroll
  for (int rep = 0; rep < 16; ++rep) {
    int rr = q4 * 16 + rep;
    Ls[rr][l] = qkv[(size_t)(s0 + rr) * 3072 + 2048 + e0 + l];
  }
  __syncthreads();
#pragma unroll
  for (int rep = 0; rep < 16; ++rep) {
    int ee = q4 * 16 + rep;
    vt[(size_t)(e0 + ee) * S + s0 + l] = Ls[l][ee];
  }
}

// ---------------- RMSNorm (bf16 in -> bf16 out) ----------------
__global__ __launch_bounds__(256) void rmsnorm_bf16_kernel(
    const short* __restrict__ xb, const float* __restrict__ g,
    short* __restrict__ out) {
  const int row = blockIdx.x;
  const int tid = threadIdx.x;
  s16x4 xv = *(const s16x4*)&xb[(size_t)row * 1024 + tid * 4];
  float x0 = bf2f(xv[0]), x1 = bf2f(xv[1]), x2 = bf2f(xv[2]), x3 = bf2f(xv[3]);
  float ss = x0 * x0 + x1 * x1 + x2 * x2 + x3 * x3;
#pragma unroll
  for (int off = 32; off; off >>= 1) ss += __shfl_xor(ss, off);
  __shared__ float red[4];
  if ((tid & 63) == 0) red[tid >> 6] = ss;
  __syncthreads();
  float tot = red[0] + red[1] + red[2] + red[3];
  float scale = rsqrtf(tot / 1024.f + 1e-6f);
  const float4 gv = *(const float4*)&g[tid * 4];
  s16x4 o;
  o[0] = f2bf(x0 * scale * gv.x);
  o[1] = f2bf(x1 * scale * gv.y);
  o[2] = f2bf(x2 * scale * gv.z);
  o[3] = f2bf(x3 * scale * gv.w);
  *(s16x4*)&out[(size_t)row * 1024 + tid * 4] = o;
}

// ---------------- 128x64 GEMM (WO): x2 = bf16(A x BT^T + x), bf16 out ----------------
__global__ __launch_bounds__(256) void gemm_bt64_kernel(
    const short* __restrict__ A, const short* __restrict__ BT,
    int M, int N, int K,
    short* __restrict__ outB, const float* __restrict__ addend) {
  __shared__ short As[128 * 32];
  __shared__ short Bs[64 * 32];
  const int tid = threadIdx.x;
  const int lane = tid & 63;
  const int wid = tid >> 6;
  const int lrow = lane & 15;
  const int kk = lane >> 4;
  const int row0 = blockIdx.y * 128;
  const int col0 = blockIdx.x * 64;
  const int wm = wid >> 1, wn = wid & 1;

  f32x4 acc[4][2] = {};

  for (int k0 = 0; k0 < K; k0 += 32) {
    __syncthreads();
#pragma unroll
    for (int it = 0; it < 2; ++it) {
      int c = it * 256 + tid;
      int r = c >> 2, c8 = (c & 3) * 8;
      const short* ga = A + (size_t)(row0 + r) * K + k0 + c8;
      short* la = &As[(size_t)(it * 256 + wid * 64) * 8];
      __builtin_amdgcn_global_load_lds(GLOBAL_AS(ga), LDS_AS(la), 16, 0, 0);
    }
    {
      int r = tid >> 2, c8 = (tid & 3) * 8;
      const short* gb = BT + (size_t)(col0 + r) * K + k0 + c8;
      short* lb = &Bs[(size_t)(wid * 64) * 8];
      __builtin_amdgcn_global_load_lds(GLOBAL_AS(gb), LDS_AS(lb), 16, 0, 0);
    }
    __syncthreads();

    bf16x8 a[4], b[2];
#pragma unroll
    for (int i = 0; i < 4; ++i)
      a[i] = *(const bf16x8*)&As[(wm * 64 + i * 16 + lrow) * 32 + kk * 8];
#pragma unroll
    for (int j = 0; j < 2; ++j)
      b[j] = *(const bf16x8*)&Bs[(wn * 32 + j * 16 + lrow) * 32 + kk * 8];
#pragma unroll
    for (int i = 0; i < 4; ++i)
#pragma unroll
      for (int j = 0; j < 2; ++j)
        acc[i][j] = __builtin_amdgcn_mfma_f32_16x16x32_bf16(a[i], b[j], acc[i][j], 0, 0, 0);
  }

#pragma unroll
  for (int i = 0; i < 4; ++i) {
    int row = row0 + wm * 64 + i * 16 + kk * 4;
#pragma unroll
    for (int j = 0; j < 2; ++j) {
      int col = col0 + wn * 32 + j * 16 + lrow;
#pragma unroll
      for (int r = 0; r < 4; ++r) {
        size_t o = (size_t)(row + r) * N + col;
        outB[o] = f2bf(acc[i][j][r] + addend[o]);
      }
    }
  }
}

// ---------------- 256x256 8-phase GEMM (T2+T3+T4+T5), bf16 out ----------------
#define READ_A(buf, mh)                                                      \
  _Pragma("unroll") for (int m4 = 0; m4 < 4; ++m4) {                         \
    int row_ = wm * 128 + ((mh)*4 + m4) * 16 + lrow;                         \
    _Pragma("unroll") for (int k_ = 0; k_ < 2; ++k_) {                       \
      int sl_ = (k_ * 4 + kk) ^ (row_ & 7);                                  \
      aA[m4][k_] = *(const bf16x8*)&lds[buf][0][row_ * 64 + sl_ * 8];        \
    }                                                                        \
  }
#define READ_B2(buf, pr)                                                     \
  _Pragma("unroll") for (int nn = 0; nn < 2; ++nn) {                         \
    int n_ = (pr)*2 + nn;                                                    \
    int row_ = wn * 64 + n_ * 16 + lrow;                                     \
    _Pragma("unroll") for (int k_ = 0; k_ < 2; ++k_) {                       \
      int sl_ = (k_ * 4 + kk) ^ (row_ & 7);                                  \
      bB[n_][k_] = *(const bf16x8*)&lds[buf][1][row_ * 64 + sl_ * 8];        \
    }                                                                        \
  }
#define MFMA16(mh, nh)                                                       \
  _Pragma("unroll") for (int m4 = 0; m4 < 4; ++m4)                           \
  _Pragma("unroll") for (int n2 = 0; n2 < 2; ++n2)                           \
  _Pragma("unroll") for (int k_ = 0; k_ < 2; ++k_)                           \
    acc[(mh)*4 + m4][(nh)*2 + n2] = __builtin_amdgcn_mfma_f32_16x16x32_bf16( \
        aA[m4][k_], bB[(nh)*2 + n2][k_], acc[(mh)*4 + m4][(nh)*2 + n2], 0, 0, 0);
#define STAGE_HALF(buf, mat, half, kt)                                       \
  {                                                                          \
    const short* g_ = ((mat) ? Bb : Ab) + (size_t)((half)*128) * K + (kt)*64;\
    short* l_ = &lds[buf][mat][(half)*8192];                                 \
    _Pragma("unroll") for (int it_ = 0; it_ < 2; ++it_) {                    \
      int ci_ = it_ * 512 + tid;                                             \
      int r_ = ci_ >> 3, sl_ = (ci_ & 7) ^ (r_ & 7);                         \
      __builtin_amdgcn_global_load_lds(GLOBAL_AS(g_ + (size_t)r_ * K + sl_ * 8), \
                                       LDS_AS(l_ + ci_ * 8), 16, 0, 0);      \
    }                                                                        \
  }
#define PH_SYNC1()                                                           \
  __builtin_amdgcn_s_barrier();                                              \
  asm volatile("s_waitcnt lgkmcnt(0)" ::: "memory");                         \
  __builtin_amdgcn_sched_barrier(0);                                         \
  __builtin_amdgcn_s_setprio(1)
#define PH_SYNC2()                                                           \
  __builtin_amdgcn_s_setprio(0);                                             \
  __builtin_amdgcn_s_barrier()
#define PH_SYNC2_VM(n)                                                       \
  __builtin_amdgcn_s_setprio(0);                                             \
  asm volatile("s_waitcnt vmcnt(" #n ")" ::: "memory");                      \
  __builtin_amdgcn_s_barrier()

template <int EPI>
__global__ __launch_bounds__(512, 2) void gemm256_kernel(
    const short* __restrict__ A, const short* __restrict__ BT,
    int N, int K, int kslice, size_t pstride,
    short* __restrict__ outB, const float* __restrict__ bias) {
  __shared__ short lds[2][2][16384];   // [buf][A/B][256 rows x 64 k], 128 KiB
  const int tid = threadIdx.x;
  const int lane = tid & 63, wid = tid >> 6;
  const int lrow = lane & 15, kk = lane >> 4;
  const int wm = wid >> 2, wn = wid & 3;
  const int row0 = blockIdx.y * 256, col0 = blockIdx.x * 256;
  const int kbase = blockIdx.z * kslice;
  const int NT = kslice >> 6;

  const short* Ab = A + (size_t)row0 * K + kbase;
  const short* Bb = BT + (size_t)col0 * K + kbase;

  f32x4 acc[8][4] = {};
  bf16x8 aA[4][2], bB[4][2];

  STAGE_HALF(0, 1, 0, 0); STAGE_HALF(0, 0, 0, 0);
  STAGE_HALF(0, 1, 1, 0); STAGE_HALF(0, 0, 1, 0);
  STAGE_HALF(1, 1, 0, 1); STAGE_HALF(1, 0, 0, 1); STAGE_HALF(1, 0, 1, 1);
  asm volatile("s_waitcnt vmcnt(6)" ::: "memory");
  __builtin_amdgcn_s_barrier();

  const int iters = NT >> 1;
  for (int i = 0; i < iters; ++i) {
    const int t1 = 2 * i + 1;
    int kt2 = 2 * i + 2; if (kt2 >= NT) kt2 -= NT;
    int kt3 = 2 * i + 3; if (kt3 >= NT) kt3 -= NT;
    READ_A(0, 0); READ_B2(0, 0); STAGE_HALF(1, 1, 1, t1);
    PH_SYNC1(); MFMA16(0, 0); PH_SYNC2();
    READ_B2(0, 1);
    PH_SYNC1(); MFMA16(0, 1); PH_SYNC2();
    READ_A(0, 1); STAGE_HALF(0, 1, 0, kt2);
    PH_SYNC1(); MFMA16(1, 0); PH_SYNC2();
    STAGE_HALF(0, 0, 0, kt2);
    PH_SYNC1(); MFMA16(1, 1); PH_SYNC2_VM(4);
    READ_A(1, 0); READ_B2(1, 0); STAGE_HALF(0, 1, 1, kt2);
    PH_SYNC1(); MFMA16(0, 0); PH_SYNC2();
    READ_B2(1, 1); STAGE_HALF(0, 0, 1, kt2);
    PH_SYNC1(); MFMA16(0, 1); PH_SYNC2();
    READ_A(1, 1); STAGE_HALF(1, 1, 0, kt3);
    PH_SYNC1(); MFMA16(1, 0); PH_SYNC2();
    STAGE_HALF(1, 0, 0, kt3); STAGE_HALF(1, 0, 1, kt3);
    PH_SYNC1(); MFMA16(1, 1); PH_SYNC2_VM(6);
  }

  short* ob = outB + (size_t)blockIdx.z * pstride;
#pragma unroll
  for (int m = 0; m < 8; ++m) {
    int row = row0 + wm * 128 + m * 16 + kk * 4;
#pragma unroll
    for (int n = 0; n < 4; ++n) {
      int col = col0 + wn * 64 + n * 16 + lrow;
#pragma unroll
      for (int r = 0; r < 4; ++r) {
        float v = acc[m][n][r];
        size_t o = (size_t)(row + r) * N + col;
        if (EPI == 0) {
          ob[o] = f2bf(v);
        } else {
          v += bias[col];
          ob[o] = f2bf(v > 0.f ? v : 0.f);
        }
      }
    }
  }
}

// out[i] = sum_{s<4} part[s][i] + bias[i % 1024] + bf2f(x2b[i])  (W2 split-K reduce)
__global__ __launch_bounds__(256) void reduce4_kernel(
    const short* __restrict__ part, const float* __restrict__ bias,
    const short* __restrict__ x2b, float* __restrict__ out) {
  const size_t MN = (size_t)4096 * 1024;
  size_t i8 = ((size_t)blockIdx.x * 256 + threadIdx.x) * 8;
  bf16x8 p0 = *(const bf16x8*)&part[i8];
  bf16x8 p1 = *(const bf16x8*)&part[MN + i8];
  bf16x8 p2 = *(const bf16x8*)&part[2 * MN + i8];
  bf16x8 p3 = *(const bf16x8*)&part[3 * MN + i8];
  bf16x8 xa = *(const bf16x8*)&x2b[i8];
  int col = (int)(i8 & 1023);
#pragma unroll
  for (int j = 0; j < 8; ++j) {
    float v = (bf2f(p0[j]) + bf2f(p1[j])) + (bf2f(p2[j]) + bf2f(p3[j]));
    out[i8 + j] = v + bias[col + j] + bf2f(xa[j]);
  }
}

// ---------------- flash attention v12 (proven): KVBLK=64, 3 blocks/CU ----------------
__device__ const unsigned char QT_SLOT[48] = {
    31, 31, 30, 15, 30, 29, 29, 28, 14, 28, 27, 27, 26, 13, 26, 25,
    25, 24, 12, 24, 23, 23, 22, 11, 22, 21, 21, 20, 10, 20, 19, 19,
    18,  9, 18, 17, 17, 16,  8, 16,  7,  6,  5,  4,  3,  2,  1,  0};
__device__ const unsigned char SP_SLOT[48] = {
    0, 1, 0, 0, 1, 0, 1, 0, 0, 1, 0, 1, 0, 0, 1, 0,
    1, 0, 0, 1, 0, 1, 0, 0, 1, 0, 1, 0, 0, 1, 0, 1,
    0, 0, 1, 0, 1, 0, 0, 1, 0, 0, 0, 0, 0, 0, 0, 0};

__global__ __launch_bounds__(512, 6) void attn_kernel(
    const short* __restrict__ QKV, const short* __restrict__ VT,
    float* __restrict__ opart, float* __restrict__ lpart,
    short* __restrict__ O) {
  const int S = 4096;
  __shared__ short Ks[2][64 * 64];
  __shared__ short Vs[2][64 * 64];
  __shared__ short Ps[8][16 * 64];

  const int tid = threadIdx.x;
  const int lane = tid & 63;
  const int w = tid >> 6;                     // 0..7
  const int lrow = lane & 15;
  const int kk = lane >> 4;
  const int bid = blockIdx.x;
  const int h = bid & 15;
  const int slot = bid >> 4;
  const int qtile = QT_SLOT[slot];
  const int sp = SP_SLOT[slot];
  const int T = 2 * qtile + 2;                // total 64-key tiles for this qtile
  const bool split = (qtile >= 16);
  const int half = qtile + 1;
  const int t0 = (split && sp) ? half : 0;
  const int t1 = (split && !sp) ? half : T;
  const int q0 = qtile * 128;
  const int qw = q0 + w * 16;                 // 16 q-rows per wave
  const int myq = qw + lrow;                  // this lane's q row (swapped layout)

  auto stage = [&](int buf, int t) {
    const int kv0 = t * 64;
    int krow = tid >> 3;                      // 64 rows x 8 slots
    int ksl = (tid & 7) ^ (krow & 7);
    const short* gk = QKV + (size_t)(kv0 + krow) * 3072 + 1024 + h * 64 + ksl * 8;
    const short* gv = VT + (size_t)(h * 64 + krow) * S + kv0 + ksl * 8;
    __builtin_amdgcn_global_load_lds(GLOBAL_AS(gk),
                                     LDS_AS(&Ks[buf][(w * 64) * 8]), 16, 0, 0);
    __builtin_amdgcn_global_load_lds(GLOBAL_AS(gv),
                                     LDS_AS(&Vs[buf][(w * 64) * 8]), 16, 0, 0);
  };

  bf16x8 qf[2];
#pragma unroll
  for (int half2 = 0; half2 < 2; ++half2)
    qf[half2] = *(const bf16x8*)&QKV[(size_t)(qw + lrow) * 3072 +
                                     h * 64 + half2 * 32 + kk * 8];

  float rs_acc = 0.f;
  f32x4 o_acc[4] = {};

  stage(0, t0);
  __syncthreads();
  int cur = 0;

  for (int t = t0; t < t1; ++t) {
    if (t + 1 < t1) stage(cur ^ 1, t + 1);    // prefetch next 64-key tile

    const int kvc = t * 64;
    if (kvc <= qw + 15) {
      // ---- QK^T (swapped): sc[c] row=key(kk*4+r), col=q(lrow) ----
      bf16x8 kf[4][2];
#pragma unroll
      for (int c = 0; c < 4; ++c)
#pragma unroll
        for (int half2 = 0; half2 < 2; ++half2) {
          int krow = c * 16 + lrow;
          kf[c][half2] = *(const bf16x8*)&Ks[cur][krow * 64 + (((half2 * 4 + kk) ^ (krow & 7)) * 8)];
        }
      f32x4 sc[4];
      __builtin_amdgcn_s_setprio(1);
#pragma unroll
      for (int c = 0; c < 4; ++c) {
        f32x4 z = {};
        z = __builtin_amdgcn_mfma_f32_16x16x32_bf16(kf[c][0], qf[0], z, 0, 0, 0);
        z = __builtin_amdgcn_mfma_f32_16x16x32_bf16(kf[c][1], qf[1], z, 0, 0, 0);
        sc[c] = z;
      }
      __builtin_amdgcn_s_setprio(0);

      // ---- softmax numerator: lane holds 4 consecutive keys for q=myq ----
      if (kvc + 63 <= qw) {
#pragma unroll
        for (int c = 0; c < 4; ++c) {
          float p0 = __expf(sc[c][0]), p1 = __expf(sc[c][1]);
          float p2 = __expf(sc[c][2]), p3 = __expf(sc[c][3]);
          rs_acc += (p0 + p1) + (p2 + p3);
          s16x4 pk;
          pk[0] = f2bf(p0); pk[1] = f2bf(p1); pk[2] = f2bf(p2); pk[3] = f2bf(p3);
          int slot8 = c * 2 + (kk >> 1);
          *(s16x4*)&Ps[w][lrow * 64 + ((slot8 ^ (lrow & 7)) * 8) + (kk & 1) * 4] = pk;
        }
      } else {
#pragma unroll
        for (int c = 0; c < 4; ++c) {
          const int keyb = kvc + c * 16 + kk * 4;
          float pv[4];
#pragma unroll
          for (int r = 0; r < 4; ++r) {
            float p = __expf(sc[c][r]);
            if (keyb + r > myq) p = 0.f;
            pv[r] = p;
          }
          rs_acc += (pv[0] + pv[1]) + (pv[2] + pv[3]);
          s16x4 pk;
          pk[0] = f2bf(pv[0]); pk[1] = f2bf(pv[1]); pk[2] = f2bf(pv[2]); pk[3] = f2bf(pv[3]);
          int slot8 = c * 2 + (kk >> 1);
          *(s16x4*)&Ps[w][lrow * 64 + ((slot8 ^ (lrow & 7)) * 8) + (kk & 1) * 4] = pk;
        }
      }

      // ---- PV over this chunk (8 MFMA) ----
#pragma unroll
      for (int ks = 0; ks < 2; ++ks) {
        bf16x8 pf2, vf[4];
        {
          int qrow = lrow;
          pf2 = *(const bf16x8*)&Ps[w][qrow * 64 + (((ks * 4 + kk) ^ (qrow & 7)) * 8)];
        }
#pragma unroll
        for (int g = 0; g < 4; ++g) {
          int erow = g * 16 + lrow;
          vf[g] = *(const bf16x8*)&Vs[cur][erow * 64 + (((ks * 4 + kk) ^ (erow & 7)) * 8)];
        }
        __builtin_amdgcn_s_setprio(1);
#pragma unroll
        for (int g = 0; g < 4; ++g)
          o_acc[g] = __builtin_amdgcn_mfma_f32_16x16x32_bf16(pf2, vf[g], o_acc[g], 0, 0, 0);
        __builtin_amdgcn_s_setprio(0);
      }
    }

    __syncthreads();                          // drain prefetch + swap
    cur ^= 1;
  }

  // ---- epilogue: 2-shuffle l reduce ----
  float l = rs_acc;
  l += __shfl_xor(l, 16);
  l += __shfl_xor(l, 32);

  if (!split) {
    float inv_[4];
#pragma unroll
    for (int r = 0; r < 4; ++r) inv_[r] = 1.f / __shfl(l, kk * 4 + r);
#pragma unroll
    for (int g = 0; g < 4; ++g)
#pragma unroll
      for (int r = 0; r < 4; ++r) {
        int s_idx = qw + kk * 4 + r;
        O[(size_t)s_idx * 1024 + h * 64 + g * 16 + lrow] =
            f2bf(o_acc[g][r] * inv_[r]);
      }
  } else {
    const int pidx = (h * 32 + qtile) * 2 + sp;
    float* op = opart + (size_t)pidx * 8192;  // [128 q][64 d]
    float* lp = lpart + pidx * 128;
    if (lane < 16) lp[w * 16 + lrow] = l;
#pragma unroll
    for (int g = 0; g < 4; ++g)
#pragma unroll
      for (int r = 0; r < 4; ++r)
        op[(w * 16 + kk * 4 + r) * 64 + g * 16 + lrow] = o_acc[g][r];
  }
}

// combine (split qtiles 16..31 only): attn_o[srow][col] = bf16( (o0+o1) / (l0+l1) )
__global__ __launch_bounds__(256) void attn_combine_kernel(
    const float* __restrict__ opart, const float* __restrict__ lpart,
    short* __restrict__ O) {
  size_t e8 = ((size_t)blockIdx.x * 256 + threadIdx.x) * 8 + (size_t)2048 * 1024;
  const int srow = (int)(e8 >> 10);
  const int col = (int)(e8 & 1023);
  const int h = col >> 6, d = col & 63;
  const int qtile = srow >> 7, qr = srow & 127;
  const int pb = (h * 32 + qtile) * 2;
  const float* o0 = opart + (size_t)pb * 8192 + qr * 64 + d;
  const float* o1 = opart + (size_t)(pb + 1) * 8192 + qr * 64 + d;
  float l = lpart[pb * 128 + qr] + lpart[(pb + 1) * 128 + qr];
  float4 a0 = *(const float4*)o0;
  float4 a1 = *(const float4*)(o0 + 4);
  float4 b0 = *(const float4*)o1;
  float4 b1 = *(const float4*)(o1 + 4);
  a0.x += b0.x; a0.y += b0.y; a0.z += b0.z; a0.w += b0.w;
  a1.x += b1.x; a1.y += b1.y; a1.z += b1.z; a1.w += b1.w;
  float inv = 1.f / l;
  bf16x8 o;
  o[0] = f2bf(a0.x * inv); o[1] = f2bf(a0.y * inv);
  o[2] = f2bf(a0.z * inv); o[3] = f2bf(a0.w * inv);
  o[4] = f2bf(a1.x * inv); o[5] = f2bf(a1.y * inv);
  o[6] = f2bf(a1.z * inv); o[7] = f2bf(a1.w * inv);
  *(bf16x8*)&O[e8] = o;
}

// ---------------- launch ----------------
extern "C" void kernel_launch(void* const* d_in, const int* in_sizes, int n_in,
                              void* d_out, int out_size, void* d_ws, size_t ws_size,
                              hipStream_t stream) {
  const float* x  = (const float*)d_in[0];
  const float* g1 = (const float*)d_in[2];
  const float* WQ = (const float*)d_in[3];
  const float* WK = (const float*)d_in[4];
  const float* WV = (const float*)d_in[5];
  const float* WO = (const float*)d_in[6];
  const float* g2 = (const float*)d_in[7];
  const float* W1 = (const float*)d_in[8];
  const float* B1 = (const float*)d_in[9];
  const float* W2 = (const float*)d_in[10];
  const float* B2 = (const float*)d_in[11];
  float* out = (float*)d_out;

  const int S = 4096, D = 1024, H = 16;

  char* ws = (char*)d_ws;
  size_t off = 0;
  auto alloc = [&](size_t bytes) -> void* {
    void* p = ws + off;
    off += (bytes + 255) & ~(size_t)255;
    return p;
  };
  short* h1     = (short*)alloc((size_t)S * D * 2);
  short* wqkv_t = (short*)alloc((size_t)3072 * 1024 * 2);
  short* qkv    = (short*)alloc((size_t)S * 3072 * 2);   // fused QKV output
  short* vt     = (short*)alloc((size_t)1024 * S * 2);
  short* attn_o = (short*)alloc((size_t)S * D * 2);
  short* wo_t   = (short*)alloc((size_t)1024 * 1024 * 2);
  short* x2b    = (short*)alloc((size_t)S * D * 2);      // bf16 residual stream
  short* h2     = (short*)alloc((size_t)S * D * 2);
  short* w1_t   = (short*)alloc((size_t)4096 * 1024 * 2);
  short* m1     = (short*)alloc((size_t)S * 4096 * 2);
  short* w2_t   = (short*)alloc((size_t)1024 * 4096 * 2);
  short* partW2 = qkv;         // W2 split-K partials (33.55MB) alias qkv(25.2)+vt(8.4) (dead by then)
  float* opart  = (float*)m1;  // attn o-partials (split qtiles only): aliases m1 (dead until W1)
  float* lpart  = (float*)h1;  // attn l-partials: 512KB (h1 dead after QKV gemm)

  // merged weight prep + rmsnorm1, one dispatch
  prep_kernel<<<dim3(3072 + S), 256, 0, stream>>>(WQ, WK, WV, wqkv_t,
                                                  WO, wo_t, W1, w1_t, W2, w2_t,
                                                  x, g1, h1);

  // attention sub-block
  gemm256_kernel<0><<<dim3(3072 / 256, S / 256, 1), 512, 0, stream>>>(
      h1, wqkv_t, 3072, 1024, 1024, 0, qkv, nullptr);
  transpose_v_kernel<<<dim3(S / 64, 1024 / 64), 256, 0, stream>>>(qkv, vt, S);
  attn_kernel<<<dim3(768), 512, 0, stream>>>(qkv, vt, opart, lpart, attn_o);
  attn_combine_kernel<<<dim3((2048 * 1024 / 8) / 256), 256, 0, stream>>>(opart, lpart, attn_o);
  // WO: x2 = bf16(attn_o @ WO + x), 128x64 tiles, 512 blocks
  gemm_bt64_kernel<<<dim3(1024 / 64, S / 128), 256, 0, stream>>>(
      attn_o, wo_t, S, 1024, 1024, x2b, x);

  // MLP sub-block
  rmsnorm_bf16_kernel<<<S, 256, 0, stream>>>(x2b, g2, h2);
  gemm256_kernel<2><<<dim3(4096 / 256, 4096 / 256, 1), 512, 0, stream>>>(
      h2, w1_t, 4096, 1024, 1024, 0, m1, B1);
  gemm256_kernel<0><<<dim3(1024 / 256, 4096 / 256, 4), 512, 0, stream>>>(
      m1, w2_t, 1024, 4096, 1024, (size_t)4096 * 1024, partW2, nullptr);
  reduce4_kernel<<<2048, 256, 0, stream>>>(partW2, B2, x2b, out);
}